// Round 4
// baseline (636.524 us; speedup 1.0000x reference)
//
#include <hip/hip_runtime.h>

typedef unsigned short u16;
typedef __attribute__((ext_vector_type(8))) __bf16 bf16x8;
typedef __attribute__((ext_vector_type(4))) float f32x4;
typedef __attribute__((ext_vector_type(16))) float f32x16;

__device__ __forceinline__ u16 f2bf(float x) {
    union { float f; unsigned int u; } v; v.f = x;
    unsigned int r = v.u + 0x7fffu + ((v.u >> 16) & 1u);
    return (u16)(r >> 16);
}
__device__ __forceinline__ unsigned int pack2bf(float a, float b) {
    return (unsigned int)f2bf(a) | ((unsigned int)f2bf(b) << 16);
}

// direct global->LDS async copy, 16B per lane. LDS dest must be wave-uniform;
// HW writes base + lane*16.
typedef const __attribute__((address_space(1))) void* gas_ptr;
typedef __attribute__((address_space(3))) void* las_ptr;
#define GLOAD_LDS16(g, l) __builtin_amdgcn_global_load_lds((gas_ptr)(const void*)(g), (las_ptr)(void*)(l), 16, 0, 0)

// ---------------- fp32 -> bf16 conversion (8 elems/thread) ----------------
__global__ void cvt_bf16(const float* __restrict__ src, u16* __restrict__ dst, int n8) {
    int i = blockIdx.x * blockDim.x + threadIdx.x;
    if (i >= n8) return;
    const float4* s = (const float4*)src + (size_t)i * 2;
    float4 a = s[0], b = s[1];
    union { u16 u[8]; uint4 v; } o;
    o.u[0] = f2bf(a.x); o.u[1] = f2bf(a.y); o.u[2] = f2bf(a.z); o.u[3] = f2bf(a.w);
    o.u[4] = f2bf(b.x); o.u[5] = f2bf(b.y); o.u[6] = f2bf(b.z); o.u[7] = f2bf(b.w);
    *((uint4*)dst + i) = o.v;
}

// ---------------- QKV projection GEMM: Y[M][3072] = X[M][1024] @ Wcat^T + bias --------
// 256x256 tile, BK=64, 8 waves (2M x 4N), per-wave 128x64 output (acc[8][4] of f32x4).
// 8-phase-style schedule (m201 port) — unchanged from round 3 (303 us, MfmaUtil 37%).
__global__ __launch_bounds__(512, 2) void gemm_qkv(
    const u16* __restrict__ X, const u16* __restrict__ W,
    const float* __restrict__ bQ, const float* __restrict__ bK,
    const float* __restrict__ bV, u16* __restrict__ Y)
{
    __shared__ __align__(16) u16 AB[2][2][16384];   // [buf][A,B][256*64] = 128 KiB
    const int tid = threadIdx.x;
    const int w = tid >> 6, lane = tid & 63;
    const int wave_m = w >> 2, wave_n = w & 3;
    const int l15 = lane & 15, l4 = lane >> 4, l7 = lane & 7;

    // bijective XCD swizzle (m204 variant; works for any nwg)
    const int nwg = gridDim.x;
    const int bid = blockIdx.x;
    const int q = nwg >> 3, r = nwg & 7;
    const int xcd = bid & 7, idx = bid >> 3;
    const int swz = (xcd < r ? xcd * (q + 1) : r * (q + 1) + (xcd - r) * q) + idx;
    const int bx = swz % 12, by = swz / 12;
    const size_t mBase = (size_t)by << 8;
    const int nBase = bx << 8;

    // staging source: lane covers 8 rows x 8 chunks per 1KB issue; logical k-chunk is
    // inverse-swizzled (lc ^ lr) so linear LDS writes produce swizzled content.
    const int lr = lane >> 3, lc = lane & 7, lcs = lc ^ lr;
    const u16* gA = X + (mBase + (size_t)(w * 32 + lr)) * 1024 + lcs * 8;
    const u16* gB = W + ((size_t)(nBase + w * 32 + lr)) * 1024 + lcs * 8;
    const int stOff = (w * 32) * 64;   // u16 offset of this wave's staging region

    f32x4 acc[8][4];
#pragma unroll
    for (int mi = 0; mi < 8; ++mi)
#pragma unroll
        for (int ni = 0; ni < 4; ++ni)
#pragma unroll
            for (int rr = 0; rr < 4; ++rr) acc[mi][ni][rr] = 0.f;

    // prologue: stage tile 0 into buf 0 (8 issues/wave), drain, barrier
#pragma unroll
    for (int j = 0; j < 4; ++j) {
        GLOAD_LDS16(gA + j * 8192, &AB[0][0][stOff + j * 512]);
        GLOAD_LDS16(gB + j * 8192, &AB[0][1][stOff + j * 512]);
    }
    asm volatile("s_waitcnt vmcnt(0)" ::: "memory");
    __builtin_amdgcn_s_barrier();
    __builtin_amdgcn_sched_barrier(0);

    const int aR = wave_m * 128 + l15;   // + mi*16
    const int bR = wave_n * 64 + l15;    // + ni*16
    const int ck0 = (l4 ^ l7) * 8;             // phys chunk byte/2 offset, ks=0
    const int ck1 = ((4 | l4) ^ l7) * 8;       // ks=1

    for (int t = 0; t < 16; ++t) {
        u16* curA = (t & 1) ? &AB[1][0][0] : &AB[0][0][0];
        u16* curB = (t & 1) ? &AB[1][1][0] : &AB[0][1][0];
        u16* stA  = (t & 1) ? &AB[0][0][stOff] : &AB[1][0][stOff];
        u16* stB  = (t & 1) ? &AB[0][1][stOff] : &AB[1][1][stOff];
        const int kNxt = (t + 1) * 64;
        const bool pf = (t < 15);

        bf16x8 a[4], b[4];
        // ---------- phase 1: mi 0-3, ks=0 ----------
#pragma unroll
        for (int ni = 0; ni < 4; ++ni)
            b[ni] = *(const bf16x8*)&curB[(bR + ni * 16) * 64 + ck0];
#pragma unroll
        for (int mi = 0; mi < 4; ++mi)
            a[mi] = *(const bf16x8*)&curA[(aR + mi * 16) * 64 + ck0];
        if (pf) {
            GLOAD_LDS16(gA + kNxt,        stA);
            GLOAD_LDS16(gA + kNxt + 8192, stA + 512);
            GLOAD_LDS16(gB + kNxt,        stB);
            GLOAD_LDS16(gB + kNxt + 8192, stB + 512);
        }
        __builtin_amdgcn_s_barrier();
        __builtin_amdgcn_s_setprio(1);
#pragma unroll
        for (int mi = 0; mi < 4; ++mi)
#pragma unroll
            for (int ni = 0; ni < 4; ++ni)
                acc[mi][ni] = __builtin_amdgcn_mfma_f32_16x16x32_bf16(a[mi], b[ni], acc[mi][ni], 0, 0, 0);
        __builtin_amdgcn_s_setprio(0);
        __builtin_amdgcn_s_barrier();

        // ---------- phase 2: mi 4-7, ks=0 (B reused) ----------
#pragma unroll
        for (int mi = 0; mi < 4; ++mi)
            a[mi] = *(const bf16x8*)&curA[(aR + (mi + 4) * 16) * 64 + ck0];
        if (pf) {
            GLOAD_LDS16(gA + kNxt + 16384, stA + 1024);
            GLOAD_LDS16(gA + kNxt + 24576, stA + 1536);
            GLOAD_LDS16(gB + kNxt + 16384, stB + 1024);
            GLOAD_LDS16(gB + kNxt + 24576, stB + 1536);
        }
        __builtin_amdgcn_s_barrier();
        __builtin_amdgcn_s_setprio(1);
#pragma unroll
        for (int mi = 0; mi < 4; ++mi)
#pragma unroll
            for (int ni = 0; ni < 4; ++ni)
                acc[mi + 4][ni] = __builtin_amdgcn_mfma_f32_16x16x32_bf16(a[mi], b[ni], acc[mi + 4][ni], 0, 0, 0);
        __builtin_amdgcn_s_setprio(0);
        __builtin_amdgcn_s_barrier();

        // ---------- phase 3: mi 0-3, ks=1 ----------
#pragma unroll
        for (int ni = 0; ni < 4; ++ni)
            b[ni] = *(const bf16x8*)&curB[(bR + ni * 16) * 64 + ck1];
#pragma unroll
        for (int mi = 0; mi < 4; ++mi)
            a[mi] = *(const bf16x8*)&curA[(aR + mi * 16) * 64 + ck1];
        __builtin_amdgcn_s_barrier();
        __builtin_amdgcn_s_setprio(1);
#pragma unroll
        for (int mi = 0; mi < 4; ++mi)
#pragma unroll
            for (int ni = 0; ni < 4; ++ni)
                acc[mi][ni] = __builtin_amdgcn_mfma_f32_16x16x32_bf16(a[mi], b[ni], acc[mi][ni], 0, 0, 0);
        __builtin_amdgcn_s_setprio(0);
        __builtin_amdgcn_s_barrier();

        // ---------- phase 4: mi 4-7, ks=1; tile-boundary drain ----------
#pragma unroll
        for (int mi = 0; mi < 4; ++mi)
            a[mi] = *(const bf16x8*)&curA[(aR + (mi + 4) * 16) * 64 + ck1];
        __builtin_amdgcn_s_barrier();
        __builtin_amdgcn_s_setprio(1);
#pragma unroll
        for (int mi = 0; mi < 4; ++mi)
#pragma unroll
            for (int ni = 0; ni < 4; ++ni)
                acc[mi + 4][ni] = __builtin_amdgcn_mfma_f32_16x16x32_bf16(a[mi], b[ni], acc[mi + 4][ni], 0, 0, 0);
        __builtin_amdgcn_s_setprio(0);
        asm volatile("s_waitcnt vmcnt(0)" ::: "memory");   // next tile's 8 loads landed (issued 3 phases ago)
        __builtin_amdgcn_s_barrier();
        __builtin_amdgcn_sched_barrier(0);
    }

    // epilogue: bias + bf16 store (C layout: col = lane&15, row = (lane>>4)*4 + r)
    const int third = nBase >> 10;
    const float* bias = (third == 0) ? bQ : ((third == 1) ? bK : bV);
    const int bcol = (nBase & 1023) + wave_n * 64 + l15;
    float bv[4];
#pragma unroll
    for (int ni = 0; ni < 4; ++ni) bv[ni] = bias[bcol + ni * 16];
#pragma unroll
    for (int mi = 0; mi < 8; ++mi) {
        size_t rb = mBase + wave_m * 128 + mi * 16 + l4 * 4;
#pragma unroll
        for (int ni = 0; ni < 4; ++ni) {
            int col = nBase + wave_n * 64 + ni * 16 + l15;
#pragma unroll
            for (int rr = 0; rr < 4; ++rr)
                Y[(rb + rr) * 3072 + col] = f2bf(acc[mi][ni][rr] + bv[ni]);
        }
    }
}

// ---------------- fused decay attention: one wave per (batch, head) ----------------
// Swapped QK^T (T12 structure): S^T = mfma(K, Q) puts one q-row's scores across a
// lane's 16 regs (+pair lane) -> rowsum = 15 in-reg adds + one shfl_xor(32); one rcp.
// coef packed to bf16 words in-register, redistributed to the PV A-fragment with
// 8 shfl_xor(32) — no coefLds, no block barrier. V staging loads issued before QK^T
// so HBM latency hides under the MFMAs.
__global__ __launch_bounds__(256) void attn_dec(
    const u16* __restrict__ Y, const int* __restrict__ lenp, float* __restrict__ out)
{
    __shared__ __align__(16) u16 vLds[4][1280];      // [20][64] bf16 per wave
    const int tid = threadIdx.x;
    const int w = tid >> 6, lane = tid & 63;
    const int u = blockIdx.x * 4 + w;
    const int b = u >> 4, h = u & 15;
    const int L = lenp[b];
    const int i32 = lane & 31, hw = lane >> 5;
    const int m19 = (i32 < 19) ? i32 : 19;

    const u16* qb = Y + (size_t)b * 61440 + h * 64;
    const u16* kb = qb + 1024;
    const u16* vb = qb + 2048;

    // issue V loads first (latency hides under QK^T MFMAs)
    uint4 vReg[3];
    int vC[3];
#pragma unroll
    for (int t = 0; t < 3; ++t) {
        int c = t * 64 + lane;
        vC[t] = c;
        if (c < 160)
            vReg[t] = *(const uint4*)(vb + (size_t)(c >> 3) * 3072 + (c & 7) * 8);
    }

    // S^T = K Q^T: A = k-rows, B = q-rows. C: row = j (k idx, reg axis), col = i (q idx) = lane&31
    f32x16 s;
    for (int r = 0; r < 16; ++r) s[r] = 0.f;
#pragma unroll
    for (int kc = 0; kc < 4; ++kc) {
        const int off = kc * 16 + hw * 8;
        bf16x8 ak = *(const bf16x8*)(kb + (size_t)m19 * 3072 + off);
        bf16x8 bq = *(const bf16x8*)(qb + (size_t)m19 * 3072 + off);
        s = __builtin_amdgcn_mfma_f32_32x32x16_bf16(ak, bq, s, 0, 0, 0);
    }

    // write V to LDS (per-wave buffer; compiler inserts lgkmcnt before PV reads)
#pragma unroll
    for (int t = 0; t < 3; ++t)
        if (vC[t] < 160) *(uint4*)&vLds[w][vC[t] * 8] = vReg[t];

    // softmax over j (reg axis): ev + in-register rowsum
    float ev[16];
    float part = 0.f;
#pragma unroll
    for (int r = 0; r < 16; ++r) {
        int j = (r & 3) + ((r >> 2) << 3) + (hw << 2);
        float e = (i32 < 20 && j < L) ? __expf(s[r] * 0.125f) : 0.f;
        ev[r] = e;
        part += e;
    }
    float sum = part + __shfl_xor(part, 32, 64);
    float inv = 1.f / (sum + 1e-8f);

    // coef[r] = ev/sum - |i-j| (i<20, j<20; else 0); pack adjacent-j pairs to u32
    unsigned int wOwn[8];
#pragma unroll
    for (int p = 0; p < 8; ++p) {
        float c01[2];
#pragma unroll
        for (int q2 = 0; q2 < 2; ++q2) {
            int r = 2 * p + q2;
            int j = (r & 3) + ((r >> 2) << 3) + (hw << 2);
            float c = ev[r] * inv;
            if (i32 < 20 && j < 20)
                c -= (float)((i32 > j) ? (i32 - j) : (j - i32));
            else
                c = 0.f;
            c01[q2] = c;
        }
        wOwn[p] = pack2bf(c01[0], c01[1]);
    }
    unsigned int wPar[8];
#pragma unroll
    for (int p = 0; p < 8; ++p)
        wPar[p] = (unsigned int)__shfl_xor((int)wOwn[p], 32, 64);

    // assemble PV A-fragments: lane l holds A[row=i32][k = hw*8+e] per kc.
    // word q of frag kc covers j pair t = 8*kc + 4*hw + q; own words cover
    // t = {0,1,4,5,8,9,12,13} + 2*hw, partner covers the complement.
    union { unsigned int u[4]; bf16x8 v; } A0, A1;
    if (hw == 0) {
        A0.u[0] = wOwn[0]; A0.u[1] = wOwn[1]; A0.u[2] = wPar[0]; A0.u[3] = wPar[1];
        A1.u[0] = wOwn[4]; A1.u[1] = wOwn[5]; A1.u[2] = wPar[4]; A1.u[3] = wPar[5];
    } else {
        A0.u[0] = wPar[2]; A0.u[1] = wPar[3]; A0.u[2] = wOwn[2]; A0.u[3] = wOwn[3];
        A1.u[0] = wPar[6]; A1.u[1] = wPar[7]; A1.u[2] = wOwn[6]; A1.u[3] = wOwn[7];
    }

    // PV: D[i][d] = sum_j coef[i][j] v[j][d] ; N=64 as two 32-col tiles, K=32
    f32x16 o0, o1;
    for (int r = 0; r < 16; ++r) { o0[r] = 0.f; o1[r] = 0.f; }
#pragma unroll
    for (int kc = 0; kc < 2; ++kc) {
        bf16x8 ac = (kc == 0) ? A0.v : A1.v;
        bf16x8 bv0, bv1;
#pragma unroll
        for (int jj = 0; jj < 8; ++jj) {
            int j = kc * 16 + hw * 8 + jj;
            int jc = (j < 19) ? j : 19;     // coef=0 for j>=20; value irrelevant, stay in-bounds
            bv0[jj] = *(const __bf16*)&vLds[w][jc * 64 + i32];
            bv1[jj] = *(const __bf16*)&vLds[w][jc * 64 + 32 + i32];
        }
        o0 = __builtin_amdgcn_mfma_f32_32x32x16_bf16(ac, bv0, o0, 0, 0, 0);
        o1 = __builtin_amdgcn_mfma_f32_32x32x16_bf16(ac, bv1, o1, 0, 0, 0);
    }

#pragma unroll
    for (int r = 0; r < 16; ++r) {
        int i = (r & 3) + ((r >> 2) << 3) + (hw << 2);
        if (i < 20) {
            size_t ro = ((size_t)b * 20 + i) * 1024 + h * 64 + i32;
            out[ro] = o0[r];
            out[ro + 32] = o1[r];
        }
    }
}

// ---------------- driver ----------------
extern "C" void kernel_launch(void* const* d_in, const int* in_sizes, int n_in,
                              void* d_out, int out_size, void* d_ws, size_t ws_size,
                              hipStream_t stream) {
    const float* Q   = (const float*)d_in[0];
    const float* W_Q = (const float*)d_in[1];
    const float* b_Q = (const float*)d_in[2];
    const float* W_K = (const float*)d_in[3];
    const float* b_K = (const float*)d_in[4];
    const float* W_V = (const float*)d_in[5];
    const float* b_V = (const float*)d_in[6];
    const int*   len = (const int*)d_in[7];
    float* out = (float*)d_out;

    // ws layout (bf16): Wbf[3072*1024] | Xbf[NB*20*1024] | Yqkv[NB*20*3072]
    // bytes needed: 6291456 + NB*163840. NB must be a multiple of 64 so NB*20 % 256 == 0.
    int NB = 2048;
    while (NB > 64 && 6291456ull + (unsigned long long)NB * 163840ull > (unsigned long long)ws_size)
        NB >>= 1;
    if (6291456ull + (unsigned long long)NB * 163840ull > (unsigned long long)ws_size)
        return;  // ws too small: leave output zeroed (diagnostic signature)

    u16* Wbf = (u16*)d_ws;
    u16* Xbf = Wbf + 3145728;
    u16* Yq  = Xbf + (size_t)NB * 20480;

    cvt_bf16<<<512, 256, 0, stream>>>(W_Q, Wbf,           131072);
    cvt_bf16<<<512, 256, 0, stream>>>(W_K, Wbf + 1048576, 131072);
    cvt_bf16<<<512, 256, 0, stream>>>(W_V, Wbf + 2097152, 131072);

    const int nsl = 2048 / NB;
    for (int sI = 0; sI < nsl; ++sI) {
        int bBase = sI * NB;
        cvt_bf16<<<NB * 10, 256, 0, stream>>>(Q + (size_t)bBase * 20480, Xbf, NB * 2560);
        int nwg = 12 * ((NB * 20) >> 8);
        gemm_qkv<<<nwg, 512, 0, stream>>>(Xbf, Wbf, b_Q, b_K, b_V, Yq);
        attn_dec<<<NB * 4, 256, 0, stream>>>(Yq, len + bBase, out + (size_t)bBase * 20480);
    }
}